// Round 2
// baseline (207.990 us; speedup 1.0000x reference)
//
#include <hip/hip_runtime.h>

#define D_FEAT 32
#define CAP 64           // per-node bucket capacity; Poisson(16) => P(deg>64) ~ 1e-18
#define OVF_CAP 65536    // overflow edge list capacity

__global__ void zero_int_kernel(int* __restrict__ p, int n) {
    int i = blockIdx.x * blockDim.x + threadIdx.x;
    if (i < n) p[i] = 0;
}

__global__ void zero_out_kernel(float* __restrict__ out, int n) {
    int i = blockIdx.x * blockDim.x + threadIdx.x;
    if (i < n) out[i] = 0.0f;
}

// Phase 1: bucket edges by destination node. One thread per edge.
__global__ void fill_buckets_kernel(const int* __restrict__ ei, int n_edges,
                                    int* __restrict__ counts,
                                    int* __restrict__ bucket,
                                    int* __restrict__ ovf_cnt,
                                    int* __restrict__ ovf_list) {
    int e = blockIdx.x * blockDim.x + threadIdx.x;
    if (e >= n_edges) return;
    int dst = ei[2 * e];
    int src = ei[2 * e + 1];
    int slot = atomicAdd(&counts[dst], 1);
    if (slot < CAP) {
        bucket[(long long)dst * CAP + slot] = src;
    } else {
        int p = atomicAdd(ovf_cnt, 1);
        if (p < OVF_CAP) { ovf_list[2 * p] = dst; ovf_list[2 * p + 1] = src; }
    }
}

// Phase 2: per-node gather + sum. 32 consecutive threads own one node
// (lane = feature). X row reads are 128B-coalesced; bucket reads broadcast.
__global__ void gather_sum_kernel(const float* __restrict__ X,
                                  const int* __restrict__ counts,
                                  const int* __restrict__ bucket,
                                  float* __restrict__ out, int n_nodes) {
    int gid = blockIdx.x * blockDim.x + threadIdx.x;
    int node = gid >> 5;
    int f = gid & 31;
    if (node >= n_nodes) return;
    int deg = counts[node];
    if (deg > CAP) deg = CAP;
    const int* b = bucket + (long long)node * CAP;
    float acc = 0.0f;
    for (int s = 0; s < deg; ++s) {
        int src = b[s];
        acc += X[(long long)src * D_FEAT + f];
    }
    out[(long long)node * D_FEAT + f] = acc;
}

// Phase 3: apply rare overflow edges with atomics (runs after gather_sum
// in stream order, so no race with the plain stores above).
__global__ void ovf_apply_kernel(const float* __restrict__ X,
                                 const int* __restrict__ ovf_list,
                                 const int* __restrict__ ovf_cnt,
                                 float* __restrict__ out) {
    int n = *ovf_cnt;
    if (n > OVF_CAP) n = OVF_CAP;
    long long total = (long long)n * D_FEAT;
    for (long long gid = blockIdx.x * blockDim.x + threadIdx.x; gid < total;
         gid += (long long)gridDim.x * blockDim.x) {
        int e = (int)(gid >> 5);
        int f = (int)(gid & 31);
        int dst = ovf_list[2 * e];
        int src = ovf_list[2 * e + 1];
        atomicAdd(&out[(long long)dst * D_FEAT + f],
                  X[(long long)src * D_FEAT + f]);
    }
}

// Fallback: round-1 pure-atomic scatter (used only if ws_size is too small).
__global__ void scatter_add_kernel(const float* __restrict__ X,
                                   const int* __restrict__ edge_index,
                                   float* __restrict__ out, int n_edges) {
    int gid = blockIdx.x * blockDim.x + threadIdx.x;
    int e = gid >> 5;
    int f = gid & 31;
    if (e >= n_edges) return;
    int dst = edge_index[2 * e];
    int src = edge_index[2 * e + 1];
    atomicAdd(&out[(long long)dst * D_FEAT + f],
              X[(long long)src * D_FEAT + f]);
}

extern "C" void kernel_launch(void* const* d_in, const int* in_sizes, int n_in,
                              void* d_out, int out_size, void* d_ws, size_t ws_size,
                              hipStream_t stream) {
    const float* X = (const float*)d_in[0];
    const int* edge_index = (const int*)d_in[1];
    float* out = (float*)d_out;

    int n_edges = in_sizes[1] / 2;
    int n_nodes = out_size / D_FEAT;

    // Workspace layout (ints):
    //   counts   [n_nodes]
    //   bucket   [n_nodes * CAP]
    //   ovf_cnt  [1]
    //   ovf_list [2 * OVF_CAP]
    long long need_ints = (long long)n_nodes * (CAP + 1) + 1 + 2LL * OVF_CAP;
    long long need_bytes = need_ints * 4;

    if ((long long)ws_size < need_bytes) {
        // Fallback: proven atomic path.
        int threads = 256;
        zero_out_kernel<<<(out_size + threads - 1) / threads, threads, 0, stream>>>(out, out_size);
        long long total = (long long)n_edges * D_FEAT;
        scatter_add_kernel<<<(int)((total + threads - 1) / threads), threads, 0, stream>>>(
            X, edge_index, out, n_edges);
        return;
    }

    int* counts = (int*)d_ws;
    int* bucket = counts + n_nodes;
    int* ovf_cnt = bucket + (long long)n_nodes * CAP;
    int* ovf_list = ovf_cnt + 1;

    int threads = 256;

    // Zero counts + ovf_cnt (contiguous: counts is first, ovf_cnt right after bucket;
    // zero them separately).
    zero_int_kernel<<<(n_nodes + threads - 1) / threads, threads, 0, stream>>>(counts, n_nodes);
    zero_int_kernel<<<1, 1, 0, stream>>>(ovf_cnt, 1);

    fill_buckets_kernel<<<(n_edges + threads - 1) / threads, threads, 0, stream>>>(
        edge_index, n_edges, counts, bucket, ovf_cnt, ovf_list);

    long long total = (long long)n_nodes * D_FEAT;
    gather_sum_kernel<<<(int)((total + threads - 1) / threads), threads, 0, stream>>>(
        X, counts, bucket, out, n_nodes);

    ovf_apply_kernel<<<256, threads, 0, stream>>>(X, ovf_list, ovf_cnt, out);
}